// Round 4
// baseline (830.601 us; speedup 1.0000x reference)
//
#include <hip/hip_runtime.h>

typedef unsigned short ushort_t;
typedef __attribute__((ext_vector_type(8))) short bf16x8;   // 8 bf16 = 4 VGPRs
typedef __attribute__((ext_vector_type(4))) float f32x4;

__device__ __forceinline__ float bflo(unsigned u) { return __uint_as_float(u << 16); }
__device__ __forceinline__ float bfhi(unsigned u) { return __uint_as_float(u & 0xffff0000u); }
__device__ __forceinline__ float bfu(ushort_t s)  { return __uint_as_float((unsigned)s << 16); }
__device__ __forceinline__ ushort_t f2bf(float f) {
    unsigned u = __float_as_uint(f);
    u = u + 0x7fffu + ((u >> 16) & 1u);   // RNE
    return (ushort_t)(u >> 16);
}
__device__ __forceinline__ void unpack8(uint4 v, float* f) {
    f[0]=bflo(v.x); f[1]=bfhi(v.x); f[2]=bflo(v.y); f[3]=bfhi(v.y);
    f[4]=bflo(v.z); f[5]=bfhi(v.z); f[6]=bflo(v.w); f[7]=bfhi(v.w);
}

// dtype-agnostic loads: f32 != 0 -> buffer holds float32, else bf16.
__device__ __forceinline__ float load1(const void* p, size_t i, int f32) {
    return f32 ? ((const float*)p)[i] : bfu(((const ushort_t*)p)[i]);
}
__device__ __forceinline__ void load8(const void* p, size_t i, int f32, float* f) {
    if (f32) {
        const float4 a = *(const float4*)((const float*)p + i);
        const float4 b = *(const float4*)((const float*)p + i + 4);
        f[0]=a.x; f[1]=a.y; f[2]=a.z; f[3]=a.w;
        f[4]=b.x; f[5]=b.y; f[6]=b.z; f[7]=b.w;
    } else {
        unpack8(*(const uint4*)((const ushort_t*)p + i), f);
    }
}
__device__ __forceinline__ void load4(const void* p, size_t i, int f32, float* f) {
    if (f32) {
        const float4 a = *(const float4*)((const float*)p + i);
        f[0]=a.x; f[1]=a.y; f[2]=a.z; f[3]=a.w;
    } else {
        const uint2 u = *(const uint2*)((const ushort_t*)p + i);
        f[0]=bflo(u.x); f[1]=bfhi(u.x); f[2]=bflo(u.y); f[3]=bfhi(u.y);
    }
}

// Inline dtype probe (wave-uniform): decode first 128 u16 halves of state1 as
// bf16. Real-bf16 randn stays <6; fp32 mantissa halves explode >1e6 w.p. ~1.
__device__ __forceinline__ int detect_f32(const ushort_t* s1h) {
    const int ln = threadIdx.x & 63;
    float v = fmaxf(fabsf(bfu(s1h[ln])), fabsf(bfu(s1h[ln + 64])));
    bool big = !(v <= 1e6f);               // NaN/Inf/large -> true
    return __ballot(big) != 0ull;
}

#define B_TOT 8192

__device__ __attribute__((aligned(16))) float    g_M[128 * 128];
__device__ __attribute__((aligned(16))) float    g_Wc1[384 * 4];
__device__ __attribute__((aligned(16))) float    g_Wv2[128 * 4];
__device__ __attribute__((aligned(16))) float    g_bc[4];
__device__ __attribute__((aligned(16))) float    g_t[B_TOT * 128];
__device__ __attribute__((aligned(16))) float    g_ogc[B_TOT * 4];
__device__ __attribute__((aligned(16))) ushort_t g_oe[B_TOT * 128];

// ---------------------------------------------------------------------------
// K1: precompute M = Wq@Wk^T, Wc1 = W1@W2, Wv2 = Wv@Wc1[128:256], bc = b1@W2+b2
// ---------------------------------------------------------------------------
__global__ __launch_bounds__(128) void k_pre(
    const void* __restrict__ Wq, const void* __restrict__ Wk,
    const void* __restrict__ Wv, const void* __restrict__ W1,
    const void* __restrict__ b1, const void* __restrict__ W2,
    const void* __restrict__ b2, const ushort_t* __restrict__ s1h)
{
    __shared__ float wq_sh[128];
    __shared__ float w2_sh[512];
    __shared__ float wc1_mid[512];
    __shared__ float redc[128][4];
    const int tid = threadIdx.x;
    const int bx = blockIdx.x;
    const int f32 = detect_f32(s1h);

    if (bx < 128) {
        wq_sh[tid] = load1(Wq, bx*128 + tid, f32);
        __syncthreads();
        float acc = 0.f;
        #pragma unroll
        for (int c = 0; c < 16; ++c) {
            float f[8]; load8(Wk, (size_t)tid*128 + c*8, f32, f);
            #pragma unroll
            for (int j = 0; j < 8; ++j) acc = fmaf(wq_sh[c*8+j], f[j], acc);
        }
        g_M[bx*128 + tid] = acc;
    } else {
        const int rbase = (bx == 128) ? 0 : ((bx == 129) ? 128 : 256);
        for (int i = tid; i < 512; i += 128) w2_sh[i] = load1(W2, i, f32);
        __syncthreads();

        const int r = rbase + tid;
        float a[4] = {0.f, 0.f, 0.f, 0.f};
        #pragma unroll
        for (int c = 0; c < 16; ++c) {
            float f[8]; load8(W1, (size_t)r*128 + c*8, f32, f);
            #pragma unroll
            for (int j = 0; j < 8; ++j) {
                const int p = c*8 + j;
                #pragma unroll
                for (int q = 0; q < 4; ++q) a[q] = fmaf(f[j], w2_sh[p*4+q], a[q]);
            }
        }
        #pragma unroll
        for (int q = 0; q < 4; ++q) g_Wc1[r*4+q] = a[q];

        if (bx == 129) {
            #pragma unroll
            for (int q = 0; q < 4; ++q) wc1_mid[tid*4+q] = a[q];
            __syncthreads();
            float v[4] = {0.f, 0.f, 0.f, 0.f};
            #pragma unroll
            for (int c = 0; c < 16; ++c) {
                float f[8]; load8(Wv, (size_t)tid*128 + c*8, f32, f);
                #pragma unroll
                for (int j = 0; j < 8; ++j) {
                    const int i2 = c*8 + j;
                    #pragma unroll
                    for (int q = 0; q < 4; ++q) v[q] = fmaf(f[j], wc1_mid[i2*4+q], v[q]);
                }
            }
            #pragma unroll
            for (int q = 0; q < 4; ++q) g_Wv2[tid*4+q] = v[q];

            const float bv = load1(b1, tid, f32);
            #pragma unroll
            for (int q = 0; q < 4; ++q) redc[tid][q] = bv * w2_sh[tid*4+q];
            __syncthreads();
            for (int s = 64; s > 0; s >>= 1) {
                if (tid < s) {
                    #pragma unroll
                    for (int q = 0; q < 4; ++q) redc[tid][q] += redc[tid+s][q];
                }
                __syncthreads();
            }
            if (tid < 4) g_bc[tid] = redc[0][tid] + load1(b2, tid, f32);
        }
    }
}

// ---------------------------------------------------------------------------
// K2: own_e = relu(state0@W_own+b_own) -> g_oe ; t = own_e @ M -> g_t
// ---------------------------------------------------------------------------
__global__ __launch_bounds__(256) void k_ownt(
    const void* __restrict__ state0, const void* __restrict__ W_own,
    const void* __restrict__ b_own, const ushort_t* __restrict__ s1h)
{
    __shared__ float s0sh[16*16];
    __shared__ float wosh[16*128];
    __shared__ float bosh[128];
    __shared__ float oesh[16*129];
    __shared__ float Mt[32][128];
    const int tid = threadIdx.x;
    const int b0 = blockIdx.x * 16;
    const int f32 = detect_f32(s1h);

    if (tid < 32) {
        float f[8]; load8(state0, (size_t)b0*16 + tid*8, f32, f);
        #pragma unroll
        for (int j = 0; j < 8; ++j) s0sh[tid*8 + j] = f[j];
    }
    {
        float f[8]; load8(W_own, (size_t)tid*8, f32, f);
        #pragma unroll
        for (int j = 0; j < 8; ++j) wosh[tid*8 + j] = f[j];
    }
    if (tid < 128) bosh[tid] = load1(b_own, tid, f32);
    __syncthreads();

    #pragma unroll
    for (int kk = 0; kk < 8; ++kk) {
        const int idx = tid + kk*256;
        const int bi = idx >> 7, h = idx & 127;
        float acc = bosh[h];
        #pragma unroll
        for (int d = 0; d < 16; ++d) acc = fmaf(s0sh[bi*16+d], wosh[d*128+h], acc);
        acc = fmaxf(acc, 0.f);
        oesh[bi*129 + h] = acc;
        g_oe[(size_t)(b0+bi)*128 + h] = f2bf(acc);
    }

    const int bi0 = (tid >> 5) * 2;
    const int h0  = (tid & 31) * 4;
    float t00=0.f,t01=0.f,t02=0.f,t03=0.f,t10=0.f,t11=0.f,t12=0.f,t13=0.f;
    for (int kt = 0; kt < 128; kt += 32) {
        __syncthreads();
        #pragma unroll
        for (int c = 0; c < 4; ++c) {
            const int i = tid + c*256;
            const int kk = i >> 5;
            const int hh = (i & 31) * 4;
            *(float4*)&Mt[kk][hh] = *(const float4*)&g_M[(size_t)(kt+kk)*128 + hh];
        }
        __syncthreads();
        #pragma unroll
        for (int k = 0; k < 32; ++k) {
            const float4 mv = *(const float4*)&Mt[k][h0];
            const float a0 = oesh[(bi0+0)*129 + kt + k];
            const float a1 = oesh[(bi0+1)*129 + kt + k];
            t00=fmaf(a0,mv.x,t00); t01=fmaf(a0,mv.y,t01); t02=fmaf(a0,mv.z,t02); t03=fmaf(a0,mv.w,t03);
            t10=fmaf(a1,mv.x,t10); t11=fmaf(a1,mv.y,t11); t12=fmaf(a1,mv.z,t12); t13=fmaf(a1,mv.w,t13);
        }
    }
    *(float4*)&g_t[(size_t)(b0+bi0+0)*128 + h0] = make_float4(t00,t01,t02,t03);
    *(float4*)&g_t[(size_t)(b0+bi0+1)*128 + h0] = make_float4(t10,t11,t12,t13);
}

// ---------------------------------------------------------------------------
// K3: ogc[b][:] = relu(state1[b]@W_grid+b_grid) @ Wc1[256:384]
// ---------------------------------------------------------------------------
__global__ __launch_bounds__(256) void k_grid(
    const void* __restrict__ state1, const void* __restrict__ W_grid,
    const void* __restrict__ b_grid)
{
    __shared__ float s1T[32][18];
    __shared__ float wg[32][128];
    __shared__ float part[32][16][4];
    const int tid = threadIdx.x;
    const int b0 = blockIdx.x * 16;
    const int f32 = detect_f32((const ushort_t*)state1);

    const int bq = tid & 7;
    const int hq = tid >> 3;
    float a00=0.f,a01=0.f,a02=0.f,a03=0.f;
    float a10=0.f,a11=0.f,a12=0.f,a13=0.f;

    for (int kt = 0; kt < 512; kt += 32) {
        if (kt) __syncthreads();
        if (tid < 128) {
            const int bb = tid >> 3;
            const int kk = (tid & 7) * 4;
            float f[4];
            load4(state1, (size_t)(b0 + bb)*512 + kt + kk, f32, f);
            #pragma unroll
            for (int j = 0; j < 4; ++j) s1T[kk + j][bb] = f[j];
        }
        {
            #pragma unroll
            for (int c = 0; c < 4; ++c) {
                const int i = tid + c*256;
                const int kk = i >> 5;
                const int hh = (i & 31) * 4;
                float f[4];
                load4(W_grid, (size_t)(kt + kk)*128 + hh, f32, f);
                *(float4*)&wg[kk][hh] = make_float4(f[0], f[1], f[2], f[3]);
            }
        }
        __syncthreads();
        #pragma unroll 8
        for (int k = 0; k < 32; ++k) {
            const float x0 = s1T[k][bq*2 + 0];
            const float x1 = s1T[k][bq*2 + 1];
            const float4 w = *(const float4*)&wg[k][hq*4];
            a00=fmaf(x0,w.x,a00); a01=fmaf(x0,w.y,a01); a02=fmaf(x0,w.z,a02); a03=fmaf(x0,w.w,a03);
            a10=fmaf(x1,w.x,a10); a11=fmaf(x1,w.y,a11); a12=fmaf(x1,w.z,a12); a13=fmaf(x1,w.w,a13);
        }
    }

    float accs[2][4] = {{a00,a01,a02,a03},{a10,a11,a12,a13}};
    float pr[2][4] = {{0,0,0,0},{0,0,0,0}};
    #pragma unroll
    for (int jh = 0; jh < 4; ++jh) {
        const int h = hq*4 + jh;
        const float bg = load1(b_grid, h, f32);
        const float4 wc = *(const float4*)&g_Wc1[(256 + h)*4];
        #pragma unroll
        for (int ib = 0; ib < 2; ++ib) {
            const float og = fmaxf(accs[ib][jh] + bg, 0.f);
            pr[ib][0] = fmaf(og, wc.x, pr[ib][0]);
            pr[ib][1] = fmaf(og, wc.y, pr[ib][1]);
            pr[ib][2] = fmaf(og, wc.z, pr[ib][2]);
            pr[ib][3] = fmaf(og, wc.w, pr[ib][3]);
        }
    }
    __syncthreads();
    #pragma unroll
    for (int j = 0; j < 4; ++j) {
        part[hq][bq*2+0][j] = pr[0][j];
        part[hq][bq*2+1][j] = pr[1][j];
    }
    __syncthreads();
    if (tid < 64) {
        const int bb = tid >> 2, j = tid & 3;
        float s = 0.f;
        #pragma unroll
        for (int q = 0; q < 32; ++q) s += part[q][bb][j];
        g_ogc[(size_t)(b0 + bb)*4 + j] = s;
    }
}

// ---------------------------------------------------------------------------
// K4 v4: one wave = one batch. v3's VALU cuts, v2's register footprint.
//   Round-3 post-mortem: ms[8] (32 VGPRs) live across pass 1 pushed the
//   unified VGPR/AGPR allocation past the occupancy cliff (208 VGPR, 11% occ,
//   1 wave/SIMD -> latency-bound collapse). Fix:
//   - mask MFMAs moved AFTER pass 1; each ms consumed immediately (transient).
//   - __launch_bounds__(256, 4): cap total regs at 128/wave -> 4 waves/SIMD.
//   - pass-2 dot uses 4 accumulators (break 32-long serial fmaf chain).
//   Keeps: bias folded into MFMA K-dim (k=20 slot), exp2-domain softmax with
//   deferred 1/den, one __syncthreads total, x_e recompute in pass 2.
// ---------------------------------------------------------------------------
__global__ __launch_bounds__(256, 4) void k_main(
    const void* __restrict__ state2, const void* __restrict__ W_intr,
    const void* __restrict__ b_intr, const ushort_t* __restrict__ s1h,
    void* __restrict__ out_raw)
{
    __shared__ __attribute__((aligned(16))) ushort_t wib[128 * 40]; // [h][k] bf16, k20=bias
    const int tid = threadIdx.x;
    const int f32 = detect_f32(s1h);

    const int wv = tid >> 6, ln = tid & 63, lq = ln >> 4, lc = ln & 15;
    const int b = blockIdx.x * 4 + wv;

    // ---- A fragments + t loads (independent of LDS stage, issue first) ----
    // row n = i*16+lc, cols k = lq*8..+7 ; k==20 -> 1.0 (bias slot), k>20 -> 0
    bf16x8 A[8];
    if (!f32) {
        const ushort_t* base = (const ushort_t*)state2 + ((size_t)b*128 + lc)*20 + lq*8;
        #pragma unroll
        for (int i = 0; i < 8; ++i) {
            uint2 p0 = make_uint2(0u, 0u), p1 = make_uint2(0u, 0u);
            if (lq < 2)       { p0 = *(const uint2*)(base + i*320); p1 = *(const uint2*)(base + i*320 + 4); }
            else if (lq == 2) { p0 = *(const uint2*)(base + i*320); p1.x = 0x00003f80u; }  // k20 = 1.0bf16
            union { bf16x8 v; uint2 u[2]; } cv;
            cv.u[0] = p0; cv.u[1] = p1;
            A[i] = cv.v;
        }
    } else {
        const float* base = (const float*)state2 + ((size_t)b*128 + lc)*20 + lq*8;
        #pragma unroll
        for (int i = 0; i < 8; ++i) {
            float f[8] = {0.f,0.f,0.f,0.f,0.f,0.f,0.f,0.f};
            if (lq < 2) {
                const float4 a4 = *(const float4*)(base + i*320);
                const float4 b4 = *(const float4*)(base + i*320 + 4);
                f[0]=a4.x; f[1]=a4.y; f[2]=a4.z; f[3]=a4.w;
                f[4]=b4.x; f[5]=b4.y; f[6]=b4.z; f[7]=b4.w;
            } else if (lq == 2) {
                const float4 a4 = *(const float4*)(base + i*320);
                f[0]=a4.x; f[1]=a4.y; f[2]=a4.z; f[3]=a4.w;
                f[4]=1.0f;                                        // bias slot
            }
            union { bf16x8 v; ushort_t h[8]; } cv;
            #pragma unroll
            for (int j = 0; j < 8; ++j) cv.h[j] = f2bf(f[j]);
            A[i] = cv.v;
        }
    }

    // t pre-scaled by log2(e)/sqrt(128): softmax runs in exp2 domain.
    float t_r[8];
    {
        const float* tb = &g_t[(size_t)b*128 + lc];
        #pragma unroll
        for (int th = 0; th < 8; ++th) t_r[th] = tb[th*16] * 0.12751743f;
    }

    // ---- stage W_intr^T -> LDS: rows 0..19 data, 20 = b_intr, 21..31 = 0 ----
    #pragma unroll
    for (int c = 0; c < 10; ++c) {
        const int idx = c*256 + tid;          // idx = d*128 + h
        const int d = idx >> 7, h = idx & 127;
        wib[h*40 + d] = f32 ? f2bf(((const float*)W_intr)[idx])
                            : ((const ushort_t*)W_intr)[idx];
    }
    if (tid < 128) {
        wib[tid*40 + 20] = f32 ? f2bf(((const float*)b_intr)[tid])
                               : ((const ushort_t*)b_intr)[tid];
        #pragma unroll
        for (int k = 21; k < 32; ++k) wib[tid*40 + k] = 0;
    }
    __syncthreads();

    const f32x4 zf = {0.f, 0.f, 0.f, 0.f};

    // ---- pass 1: sc[n] = sum_h relu(x_e[n,h]) * t[h]  (bias inside MFMA) ---
    float sc[8][4];
    #pragma unroll
    for (int i = 0; i < 8; ++i)
        #pragma unroll
        for (int r = 0; r < 4; ++r) sc[i][r] = 0.f;

    #pragma unroll
    for (int th = 0; th < 8; ++th) {
        const bf16x8 Bv = *(const bf16x8*)&wib[(th*16 + lc)*40 + lq*8];
        #pragma unroll
        for (int i = 0; i < 8; ++i) {
            const f32x4 acc = __builtin_amdgcn_mfma_f32_16x16x32_bf16(A[i], Bv, zf, 0, 0, 0);
            #pragma unroll
            for (int r = 0; r < 4; ++r)
                sc[i][r] = fmaf(fmaxf(acc[r], 0.f), t_r[th], sc[i][r]);
        }
    }
    // reduce over the 16 h-lanes (lc)
    #pragma unroll
    for (int off = 1; off < 16; off <<= 1)
        #pragma unroll
        for (int i = 0; i < 8; ++i)
            #pragma unroll
            for (int r = 0; r < 4; ++r)
                sc[i][r] += __shfl_xor(sc[i][r], off);

    // ---- mask: ones-B MFMA row-sums, consumed IMMEDIATELY (no live ms[8]) --
    {
        union { bf16x8 v; unsigned u[4]; } bo;   // 1.0 for k<20, 0 for k>=20
        bo.u[0] = (lq <= 2) ? 0x3f803f80u : 0u;
        bo.u[1] = (lq <= 2) ? 0x3f803f80u : 0u;
        bo.u[2] = (lq <= 1) ? 0x3f803f80u : 0u;
        bo.u[3] = (lq <= 1) ? 0x3f803f80u : 0u;
        #pragma unroll
        for (int i = 0; i < 8; ++i) {
            const f32x4 msv = __builtin_amdgcn_mfma_f32_16x16x32_bf16(A[i], bo.v, zf, 0, 0, 0);
            #pragma unroll
            for (int r = 0; r < 4; ++r)
                sc[i][r] = (msv[r] != 0.f) ? sc[i][r] : -1e30f;
        }
    }

    // ---- masked softmax (exp2 domain), fully in registers ------------------
    float m = -1e30f;
    #pragma unroll
    for (int i = 0; i < 8; ++i)
        m = fmaxf(m, fmaxf(fmaxf(sc[i][0], sc[i][1]), fmaxf(sc[i][2], sc[i][3])));
    m = fmaxf(m, __shfl_xor(m, 16));
    m = fmaxf(m, __shfl_xor(m, 32));

    float den = 0.f;
    #pragma unroll
    for (int i = 0; i < 8; ++i)
        #pragma unroll
        for (int r = 0; r < 4; ++r) {
            const float x = sc[i][r] - m;        // <= 0; -huge if masked -> e = 0
            const float e = __builtin_amdgcn_exp2f(x);
            sc[i][r] = e;                        // unnormalized alpha
            den += e;
        }
    den += __shfl_xor(den, 16);
    den += __shfl_xor(den, 32);
    const float rden = (m > -1e29f && den > 0.f) ? (1.f / den) : 0.f;

    // ---- pass 2: o4 += (e . relu(x_e)) * Wv2, recomputing x_e --------------
    float o4[4] = {0.f, 0.f, 0.f, 0.f};
    #pragma unroll
    for (int th = 0; th < 8; ++th) {
        const bf16x8 Bv = *(const bf16x8*)&wib[(th*16 + lc)*40 + lq*8];
        float up0 = 0.f, up1 = 0.f, up2 = 0.f, up3 = 0.f;   // 4-way ILP
        #pragma unroll
        for (int i = 0; i < 8; ++i) {
            const f32x4 acc = __builtin_amdgcn_mfma_f32_16x16x32_bf16(A[i], Bv, zf, 0, 0, 0);
            up0 = fmaf(sc[i][0], fmaxf(acc[0], 0.f), up0);
            up1 = fmaf(sc[i][1], fmaxf(acc[1], 0.f), up1);
            up2 = fmaf(sc[i][2], fmaxf(acc[2], 0.f), up2);
            up3 = fmaf(sc[i][3], fmaxf(acc[3], 0.f), up3);
        }
        const float up = (up0 + up1) + (up2 + up3);
        const float4 w2 = *(const float4*)&g_Wv2[(th*16 + lc)*4];
        o4[0] = fmaf(up, w2.x, o4[0]);
        o4[1] = fmaf(up, w2.y, o4[1]);
        o4[2] = fmaf(up, w2.z, o4[2]);
        o4[3] = fmaf(up, w2.w, o4[3]);
    }
    #pragma unroll
    for (int q = 0; q < 4; ++q) o4[q] *= rden;   // deferred softmax normalize

    // ---- own_e @ Wc1[0:128] term (h = ln and ln+64) ------------------------
    {
        const float oe0 = bfu(g_oe[(size_t)b*128 + ln]);
        const float oe1 = bfu(g_oe[(size_t)b*128 + 64 + ln]);
        const float4 wA = *(const float4*)&g_Wc1[ln*4];
        const float4 wB = *(const float4*)&g_Wc1[(64 + ln)*4];
        o4[0] += oe0*wA.x + oe1*wB.x;
        o4[1] += oe0*wA.y + oe1*wB.y;
        o4[2] += oe0*wA.z + oe1*wB.z;
        o4[3] += oe0*wA.w + oe1*wB.w;
    }

    // ---- 64-lane reduce + write -------------------------------------------
    #pragma unroll
    for (int off = 1; off < 64; off <<= 1)
        #pragma unroll
        for (int q = 0; q < 4; ++q)
            o4[q] += __shfl_xor(o4[q], off);

    if (ln == 0) {
        const float4 og = *(const float4*)&g_ogc[(size_t)b*4];
        const float v0 = g_bc[0] + og.x + o4[0];
        const float v1 = g_bc[1] + og.y + o4[1];
        const float v2 = g_bc[2] + og.z + o4[2];
        const float v3 = g_bc[3] + og.w + o4[3];
        const float l0 = fminf(fmaxf(v0, -20.f), 2.f);
        const float l1 = fminf(fmaxf(v1, -20.f), 2.f);
        const float l2 = fminf(fmaxf(v2, -20.f), 2.f);
        const float l3 = fminf(fmaxf(v3, -20.f), 2.f);
        if (f32) {
            float* of = (float*)out_raw;
            *(float4*)&of[(size_t)b*4] = make_float4(v0, v1, v2, v3);
            *(float4*)&of[((size_t)B_TOT + b)*4] = make_float4(l0, l1, l2, l3);
        } else {
            ushort_t* os = (ushort_t*)out_raw;
            uint2 mw, lw;
            mw.x = (unsigned)f2bf(v0) | ((unsigned)f2bf(v1) << 16);
            mw.y = (unsigned)f2bf(v2) | ((unsigned)f2bf(v3) << 16);
            lw.x = (unsigned)f2bf(l0) | ((unsigned)f2bf(l1) << 16);
            lw.y = (unsigned)f2bf(l2) | ((unsigned)f2bf(l3) << 16);
            *(uint2*)&os[(size_t)b*4] = mw;
            *(uint2*)&os[((size_t)B_TOT + b)*4] = lw;
        }
    }
}

// ---------------------------------------------------------------------------
extern "C" void kernel_launch(void* const* d_in, const int* in_sizes, int n_in,
                              void* d_out, int out_size, void* d_ws, size_t ws_size,
                              hipStream_t stream)
{
    (void)in_sizes; (void)n_in; (void)out_size; (void)d_ws; (void)ws_size;
    const void* state0 = d_in[0];
    const void* state1 = d_in[1];
    const void* state2 = d_in[2];
    const void* W_own  = d_in[3];
    const void* b_own  = d_in[4];
    const void* W_intr = d_in[5];
    const void* b_intr = d_in[6];
    const void* W_grid = d_in[7];
    const void* b_grid = d_in[8];
    const void* Wq     = d_in[9];
    const void* Wk     = d_in[10];
    const void* Wv     = d_in[11];
    const void* W1     = d_in[12];
    const void* b1     = d_in[13];
    const void* W2     = d_in[14];
    const void* b2     = d_in[15];
    const ushort_t* s1h = (const ushort_t*)state1;

    k_pre  <<<dim3(131),  dim3(128), 0, stream>>>(Wq, Wk, Wv, W1, b1, W2, b2, s1h);
    k_ownt <<<dim3(512),  dim3(256), 0, stream>>>(state0, W_own, b_own, s1h);
    k_grid <<<dim3(512),  dim3(256), 0, stream>>>(state1, W_grid, b_grid);
    k_main <<<dim3(2048), dim3(256), 0, stream>>>(state2, W_intr, b_intr, s1h, d_out);
}

// Round 7
// 304.603 us; speedup vs baseline: 2.7268x; 2.7268x over previous
//
#include <hip/hip_runtime.h>

typedef unsigned short ushort_t;
typedef __attribute__((ext_vector_type(8))) short bf16x8;   // 8 bf16 = 4 VGPRs
typedef __attribute__((ext_vector_type(4))) float f32x4;

__device__ __forceinline__ float bflo(unsigned u) { return __uint_as_float(u << 16); }
__device__ __forceinline__ float bfhi(unsigned u) { return __uint_as_float(u & 0xffff0000u); }
__device__ __forceinline__ float bfu(ushort_t s)  { return __uint_as_float((unsigned)s << 16); }
__device__ __forceinline__ ushort_t f2bf(float f) {
    unsigned u = __float_as_uint(f);
    u = u + 0x7fffu + ((u >> 16) & 1u);   // RNE
    return (ushort_t)(u >> 16);
}
__device__ __forceinline__ void unpack8(uint4 v, float* f) {
    f[0]=bflo(v.x); f[1]=bfhi(v.x); f[2]=bflo(v.y); f[3]=bfhi(v.y);
    f[4]=bflo(v.z); f[5]=bfhi(v.z); f[6]=bflo(v.w); f[7]=bfhi(v.w);
}

// dtype-agnostic loads: f32 != 0 -> buffer holds float32, else bf16.
__device__ __forceinline__ float load1(const void* p, size_t i, int f32) {
    return f32 ? ((const float*)p)[i] : bfu(((const ushort_t*)p)[i]);
}
__device__ __forceinline__ void load8(const void* p, size_t i, int f32, float* f) {
    if (f32) {
        const float4 a = *(const float4*)((const float*)p + i);
        const float4 b = *(const float4*)((const float*)p + i + 4);
        f[0]=a.x; f[1]=a.y; f[2]=a.z; f[3]=a.w;
        f[4]=b.x; f[5]=b.y; f[6]=b.z; f[7]=b.w;
    } else {
        unpack8(*(const uint4*)((const ushort_t*)p + i), f);
    }
}
__device__ __forceinline__ void load4(const void* p, size_t i, int f32, float* f) {
    if (f32) {
        const float4 a = *(const float4*)((const float*)p + i);
        f[0]=a.x; f[1]=a.y; f[2]=a.z; f[3]=a.w;
    } else {
        const uint2 u = *(const uint2*)((const ushort_t*)p + i);
        f[0]=bflo(u.x); f[1]=bfhi(u.x); f[2]=bflo(u.y); f[3]=bfhi(u.y);
    }
}

// Inline dtype probe (wave-uniform): decode first 128 u16 halves of state1 as
// bf16. Real-bf16 randn stays <6; fp32 mantissa halves explode >1e6 w.p. ~1.
__device__ __forceinline__ int detect_f32(const ushort_t* s1h) {
    const int ln = threadIdx.x & 63;
    float v = fmaxf(fabsf(bfu(s1h[ln])), fabsf(bfu(s1h[ln + 64])));
    bool big = !(v <= 1e6f);               // NaN/Inf/large -> true
    return __ballot(big) != 0ull;
}

#define B_TOT 8192

__device__ __attribute__((aligned(16))) float    g_M[128 * 128];
__device__ __attribute__((aligned(16))) float    g_Wc1[384 * 4];
__device__ __attribute__((aligned(16))) float    g_Wv2[128 * 4];
__device__ __attribute__((aligned(16))) float    g_bc[4];
__device__ __attribute__((aligned(16))) float    g_t[B_TOT * 128];
__device__ __attribute__((aligned(16))) float    g_ogc[B_TOT * 4];
__device__ __attribute__((aligned(16))) ushort_t g_oe[B_TOT * 128];
// Laundering offset: always 0, but volatile -> compiler cannot prove it, so
// pass-2 reloads via (state2 + g_zero0) cannot CSE with pass-1 loads.
__device__ volatile unsigned g_zero0 = 0u;

// ---------------------------------------------------------------------------
// K1: precompute M = Wq@Wk^T, Wc1 = W1@W2, Wv2 = Wv@Wc1[128:256], bc = b1@W2+b2
// ---------------------------------------------------------------------------
__global__ __launch_bounds__(128) void k_pre(
    const void* __restrict__ Wq, const void* __restrict__ Wk,
    const void* __restrict__ Wv, const void* __restrict__ W1,
    const void* __restrict__ b1, const void* __restrict__ W2,
    const void* __restrict__ b2, const ushort_t* __restrict__ s1h)
{
    __shared__ float wq_sh[128];
    __shared__ float w2_sh[512];
    __shared__ float wc1_mid[512];
    __shared__ float redc[128][4];
    const int tid = threadIdx.x;
    const int bx = blockIdx.x;
    const int f32 = detect_f32(s1h);

    if (bx < 128) {
        wq_sh[tid] = load1(Wq, bx*128 + tid, f32);
        __syncthreads();
        float acc = 0.f;
        #pragma unroll
        for (int c = 0; c < 16; ++c) {
            float f[8]; load8(Wk, (size_t)tid*128 + c*8, f32, f);
            #pragma unroll
            for (int j = 0; j < 8; ++j) acc = fmaf(wq_sh[c*8+j], f[j], acc);
        }
        g_M[bx*128 + tid] = acc;
    } else {
        const int rbase = (bx == 128) ? 0 : ((bx == 129) ? 128 : 256);
        for (int i = tid; i < 512; i += 128) w2_sh[i] = load1(W2, i, f32);
        __syncthreads();

        const int r = rbase + tid;
        float a[4] = {0.f, 0.f, 0.f, 0.f};
        #pragma unroll
        for (int c = 0; c < 16; ++c) {
            float f[8]; load8(W1, (size_t)r*128 + c*8, f32, f);
            #pragma unroll
            for (int j = 0; j < 8; ++j) {
                const int p = c*8 + j;
                #pragma unroll
                for (int q = 0; q < 4; ++q) a[q] = fmaf(f[j], w2_sh[p*4+q], a[q]);
            }
        }
        #pragma unroll
        for (int q = 0; q < 4; ++q) g_Wc1[r*4+q] = a[q];

        if (bx == 129) {
            #pragma unroll
            for (int q = 0; q < 4; ++q) wc1_mid[tid*4+q] = a[q];
            __syncthreads();
            float v[4] = {0.f, 0.f, 0.f, 0.f};
            #pragma unroll
            for (int c = 0; c < 16; ++c) {
                float f[8]; load8(Wv, (size_t)tid*128 + c*8, f32, f);
                #pragma unroll
                for (int j = 0; j < 8; ++j) {
                    const int i2 = c*8 + j;
                    #pragma unroll
                    for (int q = 0; q < 4; ++q) v[q] = fmaf(f[j], wc1_mid[i2*4+q], v[q]);
                }
            }
            #pragma unroll
            for (int q = 0; q < 4; ++q) g_Wv2[tid*4+q] = v[q];

            const float bv = load1(b1, tid, f32);
            #pragma unroll
            for (int q = 0; q < 4; ++q) redc[tid][q] = bv * w2_sh[tid*4+q];
            __syncthreads();
            for (int s = 64; s > 0; s >>= 1) {
                if (tid < s) {
                    #pragma unroll
                    for (int q = 0; q < 4; ++q) redc[tid][q] += redc[tid+s][q];
                }
                __syncthreads();
            }
            if (tid < 4) g_bc[tid] = redc[0][tid] + load1(b2, tid, f32);
        }
    }
}

// ---------------------------------------------------------------------------
// K2: own_e = relu(state0@W_own+b_own) -> g_oe ; t = own_e @ M -> g_t
// ---------------------------------------------------------------------------
__global__ __launch_bounds__(256) void k_ownt(
    const void* __restrict__ state0, const void* __restrict__ W_own,
    const void* __restrict__ b_own, const ushort_t* __restrict__ s1h)
{
    __shared__ float s0sh[16*16];
    __shared__ float wosh[16*128];
    __shared__ float bosh[128];
    __shared__ float oesh[16*129];
    __shared__ float Mt[32][128];
    const int tid = threadIdx.x;
    const int b0 = blockIdx.x * 16;
    const int f32 = detect_f32(s1h);

    if (tid < 32) {
        float f[8]; load8(state0, (size_t)b0*16 + tid*8, f32, f);
        #pragma unroll
        for (int j = 0; j < 8; ++j) s0sh[tid*8 + j] = f[j];
    }
    {
        float f[8]; load8(W_own, (size_t)tid*8, f32, f);
        #pragma unroll
        for (int j = 0; j < 8; ++j) wosh[tid*8 + j] = f[j];
    }
    if (tid < 128) bosh[tid] = load1(b_own, tid, f32);
    __syncthreads();

    #pragma unroll
    for (int kk = 0; kk < 8; ++kk) {
        const int idx = tid + kk*256;
        const int bi = idx >> 7, h = idx & 127;
        float acc = bosh[h];
        #pragma unroll
        for (int d = 0; d < 16; ++d) acc = fmaf(s0sh[bi*16+d], wosh[d*128+h], acc);
        acc = fmaxf(acc, 0.f);
        oesh[bi*129 + h] = acc;
        g_oe[(size_t)(b0+bi)*128 + h] = f2bf(acc);
    }

    const int bi0 = (tid >> 5) * 2;
    const int h0  = (tid & 31) * 4;
    float t00=0.f,t01=0.f,t02=0.f,t03=0.f,t10=0.f,t11=0.f,t12=0.f,t13=0.f;
    for (int kt = 0; kt < 128; kt += 32) {
        __syncthreads();
        #pragma unroll
        for (int c = 0; c < 4; ++c) {
            const int i = tid + c*256;
            const int kk = i >> 5;
            const int hh = (i & 31) * 4;
            *(float4*)&Mt[kk][hh] = *(const float4*)&g_M[(size_t)(kt+kk)*128 + hh];
        }
        __syncthreads();
        #pragma unroll
        for (int k = 0; k < 32; ++k) {
            const float4 mv = *(const float4*)&Mt[k][h0];
            const float a0 = oesh[(bi0+0)*129 + kt + k];
            const float a1 = oesh[(bi0+1)*129 + kt + k];
            t00=fmaf(a0,mv.x,t00); t01=fmaf(a0,mv.y,t01); t02=fmaf(a0,mv.z,t02); t03=fmaf(a0,mv.w,t03);
            t10=fmaf(a1,mv.x,t10); t11=fmaf(a1,mv.y,t11); t12=fmaf(a1,mv.z,t12); t13=fmaf(a1,mv.w,t13);
        }
    }
    *(float4*)&g_t[(size_t)(b0+bi0+0)*128 + h0] = make_float4(t00,t01,t02,t03);
    *(float4*)&g_t[(size_t)(b0+bi0+1)*128 + h0] = make_float4(t10,t11,t12,t13);
}

// ---------------------------------------------------------------------------
// K3: ogc[b][:] = relu(state1[b]@W_grid+b_grid) @ Wc1[256:384]
// ---------------------------------------------------------------------------
__global__ __launch_bounds__(256) void k_grid(
    const void* __restrict__ state1, const void* __restrict__ W_grid,
    const void* __restrict__ b_grid)
{
    __shared__ float s1T[32][18];
    __shared__ float wg[32][128];
    __shared__ float part[32][16][4];
    const int tid = threadIdx.x;
    const int b0 = blockIdx.x * 16;
    const int f32 = detect_f32((const ushort_t*)state1);

    const int bq = tid & 7;
    const int hq = tid >> 3;
    float a00=0.f,a01=0.f,a02=0.f,a03=0.f;
    float a10=0.f,a11=0.f,a12=0.f,a13=0.f;

    for (int kt = 0; kt < 512; kt += 32) {
        if (kt) __syncthreads();
        if (tid < 128) {
            const int bb = tid >> 3;
            const int kk = (tid & 7) * 4;
            float f[4];
            load4(state1, (size_t)(b0 + bb)*512 + kt + kk, f32, f);
            #pragma unroll
            for (int j = 0; j < 4; ++j) s1T[kk + j][bb] = f[j];
        }
        {
            #pragma unroll
            for (int c = 0; c < 4; ++c) {
                const int i = tid + c*256;
                const int kk = i >> 5;
                const int hh = (i & 31) * 4;
                float f[4];
                load4(W_grid, (size_t)(kt + kk)*128 + hh, f32, f);
                *(float4*)&wg[kk][hh] = make_float4(f[0], f[1], f[2], f[3]);
            }
        }
        __syncthreads();
        #pragma unroll 8
        for (int k = 0; k < 32; ++k) {
            const float x0 = s1T[k][bq*2 + 0];
            const float x1 = s1T[k][bq*2 + 1];
            const float4 w = *(const float4*)&wg[k][hq*4];
            a00=fmaf(x0,w.x,a00); a01=fmaf(x0,w.y,a01); a02=fmaf(x0,w.z,a02); a03=fmaf(x0,w.w,a03);
            a10=fmaf(x1,w.x,a10); a11=fmaf(x1,w.y,a11); a12=fmaf(x1,w.z,a12); a13=fmaf(x1,w.w,a13);
        }
    }

    float accs[2][4] = {{a00,a01,a02,a03},{a10,a11,a12,a13}};
    float pr[2][4] = {{0,0,0,0},{0,0,0,0}};
    #pragma unroll
    for (int jh = 0; jh < 4; ++jh) {
        const int h = hq*4 + jh;
        const float bg = load1(b_grid, h, f32);
        const float4 wc = *(const float4*)&g_Wc1[(256 + h)*4];
        #pragma unroll
        for (int ib = 0; ib < 2; ++ib) {
            const float og = fmaxf(accs[ib][jh] + bg, 0.f);
            pr[ib][0] = fmaf(og, wc.x, pr[ib][0]);
            pr[ib][1] = fmaf(og, wc.y, pr[ib][1]);
            pr[ib][2] = fmaf(og, wc.z, pr[ib][2]);
            pr[ib][3] = fmaf(og, wc.w, pr[ib][3]);
        }
    }
    __syncthreads();
    #pragma unroll
    for (int j = 0; j < 4; ++j) {
        part[hq][bq*2+0][j] = pr[0][j];
        part[hq][bq*2+1][j] = pr[1][j];
    }
    __syncthreads();
    if (tid < 64) {
        const int bb = tid >> 2, j = tid & 3;
        float s = 0.f;
        #pragma unroll
        for (int q = 0; q < 32; ++q) s += part[q][bb][j];
        g_ogc[(size_t)(b0 + bb)*4 + j] = s;
    }
}

// ---------------------------------------------------------------------------
// A-fragment loader for k_main: row n = i*16+lc, cols k = lq*8..+7.
// k==20 -> 1.0 (bias slot), k>20 -> 0.
// ---------------------------------------------------------------------------
__device__ __forceinline__ void load_A(bf16x8* A, const void* state2,
                                       int b, int lc, int lq, int f32)
{
    if (!f32) {
        const ushort_t* base = (const ushort_t*)state2 + ((size_t)b*128 + lc)*20 + lq*8;
        #pragma unroll
        for (int i = 0; i < 8; ++i) {
            uint2 p0 = make_uint2(0u, 0u), p1 = make_uint2(0u, 0u);
            if (lq < 2)       { p0 = *(const uint2*)(base + i*320); p1 = *(const uint2*)(base + i*320 + 4); }
            else if (lq == 2) { p0 = *(const uint2*)(base + i*320); p1.x = 0x00003f80u; }  // k20 = 1.0bf16
            union { bf16x8 v; uint2 u[2]; } cv;
            cv.u[0] = p0; cv.u[1] = p1;
            A[i] = cv.v;
        }
    } else {
        const float* base = (const float*)state2 + ((size_t)b*128 + lc)*20 + lq*8;
        #pragma unroll
        for (int i = 0; i < 8; ++i) {
            float f[8] = {0.f,0.f,0.f,0.f,0.f,0.f,0.f,0.f};
            if (lq < 2) {
                const float4 a4 = *(const float4*)(base + i*320);
                const float4 b4 = *(const float4*)(base + i*320 + 4);
                f[0]=a4.x; f[1]=a4.y; f[2]=a4.z; f[3]=a4.w;
                f[4]=b4.x; f[5]=b4.y; f[6]=b4.z; f[7]=b4.w;
            } else if (lq == 2) {
                const float4 a4 = *(const float4*)(base + i*320);
                f[0]=a4.x; f[1]=a4.y; f[2]=a4.z; f[3]=a4.w;
                f[4]=1.0f;                                        // bias slot
            }
            union { bf16x8 v; ushort_t h[8]; } cv;
            #pragma unroll
            for (int j = 0; j < 8; ++j) cv.h[j] = f2bf(f[j]);
            A[i] = cv.v;
        }
    }
}

// ---------------------------------------------------------------------------
// K4 v5c: one wave = one batch; NO A live range across softmax.
//   (v5 resubmit #2; inline asm removed entirely — rounds 2/5/6 all failed
//   infra with asm present, rounds 0/1/3/4 all ran asm-free. Laundering now
//   via volatile device global g_zero0: compiler cannot prove the offset is
//   0, so pass-2 loads cannot CSE with pass-1's.)
//   History: v3 keep-A-live = 208 VGPR, 11% occ (cliff). v4's
//   launch_bounds(256,4) = scratch spill, WRITE 1.1GB, 609us. v2's hidden
//   win was compiler rematerializing A from global. v5 makes that explicit:
//   pass 1 loads A (dies at mask-MFMAs); softmax in regs; pass 2 reloads A2
//   via laundered pointer (L2-hot, ~20KB/block). Peak pressure =
//   max(pass1, pass2) ~ 90-110 VGPR. No launch-bounds cap.
//   Keeps: bias-in-K (k=20 slot), mask via ones-B MFMA consumed immediately,
//   exp2-domain softmax, deferred 1/den, 4-way ILP pass-2 dot, 1 barrier.
// ---------------------------------------------------------------------------
__global__ __launch_bounds__(256) void k_main(
    const void* __restrict__ state2, const void* __restrict__ W_intr,
    const void* __restrict__ b_intr, const ushort_t* __restrict__ s1h,
    void* __restrict__ out_raw)
{
    __shared__ __attribute__((aligned(16))) ushort_t wib[128 * 40]; // [h][k] bf16, k20=bias
    const int tid = threadIdx.x;
    const int f32 = detect_f32(s1h);

    const int wv = tid >> 6, ln = tid & 63, lq = ln >> 4, lc = ln & 15;
    const int b = blockIdx.x * 4 + wv;

    // ---- stage W_intr^T -> LDS: rows 0..19 data, 20 = b_intr, 21..31 = 0 ----
    #pragma unroll
    for (int c = 0; c < 10; ++c) {
        const int idx = c*256 + tid;          // idx = d*128 + h
        const int d = idx >> 7, h = idx & 127;
        wib[h*40 + d] = f32 ? f2bf(((const float*)W_intr)[idx])
                            : ((const ushort_t*)W_intr)[idx];
    }
    if (tid < 128) {
        wib[tid*40 + 20] = f32 ? f2bf(((const float*)b_intr)[tid])
                               : ((const ushort_t*)b_intr)[tid];
        #pragma unroll
        for (int k = 21; k < 32; ++k) wib[tid*40 + k] = 0;
    }

    // t pre-scaled by log2(e)/sqrt(128): softmax runs in exp2 domain.
    float t_r[8];
    {
        const float* tb = &g_t[(size_t)b*128 + lc];
        #pragma unroll
        for (int th = 0; th < 8; ++th) t_r[th] = tb[th*16] * 0.12751743f;
    }
    __syncthreads();

    const f32x4 zf = {0.f, 0.f, 0.f, 0.f};

    // ======================= pass 1 (A lives only here) =====================
    float sc[8][4];
    {
        bf16x8 A[8];
        load_A(A, state2, b, lc, lq, f32);

        #pragma unroll
        for (int i = 0; i < 8; ++i)
            #pragma unroll
            for (int r = 0; r < 4; ++r) sc[i][r] = 0.f;

        #pragma unroll
        for (int th = 0; th < 8; ++th) {
            const bf16x8 Bv = *(const bf16x8*)&wib[(th*16 + lc)*40 + lq*8];
            #pragma unroll
            for (int i = 0; i < 8; ++i) {
                const f32x4 acc = __builtin_amdgcn_mfma_f32_16x16x32_bf16(A[i], Bv, zf, 0, 0, 0);
                #pragma unroll
                for (int r = 0; r < 4; ++r)
                    sc[i][r] = fmaf(fmaxf(acc[r], 0.f), t_r[th], sc[i][r]);
            }
        }
        // reduce over the 16 h-lanes (lc)
        #pragma unroll
        for (int off = 1; off < 16; off <<= 1)
            #pragma unroll
            for (int i = 0; i < 8; ++i)
                #pragma unroll
                for (int r = 0; r < 4; ++r)
                    sc[i][r] += __shfl_xor(sc[i][r], off);

        // mask: ones-B MFMA row-sums, consumed immediately (A's last use)
        union { bf16x8 v; unsigned u[4]; } bo;   // 1.0 for k<20, 0 for k>=20
        bo.u[0] = (lq <= 2) ? 0x3f803f80u : 0u;
        bo.u[1] = (lq <= 2) ? 0x3f803f80u : 0u;
        bo.u[2] = (lq <= 1) ? 0x3f803f80u : 0u;
        bo.u[3] = (lq <= 1) ? 0x3f803f80u : 0u;
        #pragma unroll
        for (int i = 0; i < 8; ++i) {
            const f32x4 msv = __builtin_amdgcn_mfma_f32_16x16x32_bf16(A[i], bo.v, zf, 0, 0, 0);
            #pragma unroll
            for (int r = 0; r < 4; ++r)
                sc[i][r] = (msv[r] != 0.f) ? sc[i][r] : -1e30f;
        }
    }   // ---- A dead here ----

    // ---- masked softmax (exp2 domain), fully in registers ------------------
    float m = -1e30f;
    #pragma unroll
    for (int i = 0; i < 8; ++i)
        m = fmaxf(m, fmaxf(fmaxf(sc[i][0], sc[i][1]), fmaxf(sc[i][2], sc[i][3])));
    m = fmaxf(m, __shfl_xor(m, 16));
    m = fmaxf(m, __shfl_xor(m, 32));

    float den = 0.f;
    #pragma unroll
    for (int i = 0; i < 8; ++i)
        #pragma unroll
        for (int r = 0; r < 4; ++r) {
            const float x = sc[i][r] - m;        // <= 0; -huge if masked -> e = 0
            const float e = __builtin_amdgcn_exp2f(x);
            sc[i][r] = e;                        // unnormalized alpha
            den += e;
        }
    den += __shfl_xor(den, 16);
    den += __shfl_xor(den, 32);
    const float rden = (m > -1e29f && den > 0.f) ? (1.f / den) : 0.f;

    // ======================= pass 2 (A2 reloaded, laundered) ================
    // g_zero0 is a volatile device global that always reads 0; the compiler
    // cannot prove it, so these loads are not CSE-able with pass 1's (that
    // CSE is what recreated the 208-VGPR cross-softmax live range in v3).
    const size_t zoff = (size_t)g_zero0;
    const void* s2p = (const void*)((const char*)state2 + zoff);
    bf16x8 A2[8];
    load_A(A2, s2p, b, lc, lq, f32);

    float o4[4] = {0.f, 0.f, 0.f, 0.f};
    #pragma unroll
    for (int th = 0; th < 8; ++th) {
        const bf16x8 Bv = *(const bf16x8*)&wib[(th*16 + lc)*40 + lq*8];
        float up0 = 0.f, up1 = 0.f, up2 = 0.f, up3 = 0.f;   // 4-way ILP
        #pragma unroll
        for (int i = 0; i < 8; ++i) {
            const f32x4 acc = __builtin_amdgcn_mfma_f32_16x16x32_bf16(A2[i], Bv, zf, 0, 0, 0);
            up0 = fmaf(sc[i][0], fmaxf(acc[0], 0.f), up0);
            up1 = fmaf(sc[i][1], fmaxf(acc[1], 0.f), up1);
            up2 = fmaf(sc[i][2], fmaxf(acc[2], 0.f), up2);
            up3 = fmaf(sc[i][3], fmaxf(acc[3], 0.f), up3);
        }
        const float up = (up0 + up1) + (up2 + up3);
        const float4 w2 = *(const float4*)&g_Wv2[(th*16 + lc)*4];
        o4[0] = fmaf(up, w2.x, o4[0]);
        o4[1] = fmaf(up, w2.y, o4[1]);
        o4[2] = fmaf(up, w2.z, o4[2]);
        o4[3] = fmaf(up, w2.w, o4[3]);
    }
    #pragma unroll
    for (int q = 0; q < 4; ++q) o4[q] *= rden;   // deferred softmax normalize

    // ---- own_e @ Wc1[0:128] term (h = ln and ln+64) ------------------------
    {
        const float oe0 = bfu(g_oe[(size_t)b*128 + ln]);
        const float oe1 = bfu(g_oe[(size_t)b*128 + 64 + ln]);
        const float4 wA = *(const float4*)&g_Wc1[ln*4];
        const float4 wB = *(const float4*)&g_Wc1[(64 + ln)*4];
        o4[0] += oe0*wA.x + oe1*wB.x;
        o4[1] += oe0*wA.y + oe1*wB.y;
        o4[2] += oe0*wA.z + oe1*wB.z;
        o4[3] += oe0*wA.w + oe1*wB.w;
    }

    // ---- 64-lane reduce + write -------------------------------------------
    #pragma unroll
    for (int off = 1; off < 64; off <<= 1)
        #pragma unroll
        for (int q = 0; q < 4; ++q)
            o4[q] += __shfl_xor(o4[q], off);

    if (ln == 0) {
        const float4 og = *(const float4*)&g_ogc[(size_t)b*4];
        const float v0 = g_bc[0] + og.x + o4[0];
        const float v1 = g_bc[1] + og.y + o4[1];
        const float v2 = g_bc[2] + og.z + o4[2];
        const float v3 = g_bc[3] + og.w + o4[3];
        const float l0 = fminf(fmaxf(v0, -20.f), 2.f);
        const float l1 = fminf(fmaxf(v1, -20.f), 2.f);
        const float l2 = fminf(fmaxf(v2, -20.f), 2.f);
        const float l3 = fminf(fmaxf(v3, -20.f), 2.f);
        if (f32) {
            float* of = (float*)out_raw;
            *(float4*)&of[(size_t)b*4] = make_float4(v0, v1, v2, v3);
            *(float4*)&of[((size_t)B_TOT + b)*4] = make_float4(l0, l1, l2, l3);
        } else {
            ushort_t* os = (ushort_t*)out_raw;
            uint2 mw, lw;
            mw.x = (unsigned)f2bf(v0) | ((unsigned)f2bf(v1) << 16);
            mw.y = (unsigned)f2bf(v2) | ((unsigned)f2bf(v3) << 16);
            lw.x = (unsigned)f2bf(l0) | ((unsigned)f2bf(l1) << 16);
            lw.y = (unsigned)f2bf(l2) | ((unsigned)f2bf(l3) << 16);
            *(uint2*)&os[(size_t)b*4] = mw;
            *(uint2*)&os[((size_t)B_TOT + b)*4] = lw;
        }
    }
}

// ---------------------------------------------------------------------------
extern "C" void kernel_launch(void* const* d_in, const int* in_sizes, int n_in,
                              void* d_out, int out_size, void* d_ws, size_t ws_size,
                              hipStream_t stream)
{
    (void)in_sizes; (void)n_in; (void)out_size; (void)d_ws; (void)ws_size;
    const void* state0 = d_in[0];
    const void* state1 = d_in[1];
    const void* state2 = d_in[2];
    const void* W_own  = d_in[3];
    const void* b_own  = d_in[4];
    const void* W_intr = d_in[5];
    const void* b_intr = d_in[6];
    const void* W_grid = d_in[7];
    const void* b_grid = d_in[8];
    const void* Wq     = d_in[9];
    const void* Wk     = d_in[10];
    const void* Wv     = d_in[11];
    const void* W1     = d_in[12];
    const void* b1     = d_in[13];
    const void* W2     = d_in[14];
    const void* b2     = d_in[15];
    const ushort_t* s1h = (const ushort_t*)state1;

    k_pre  <<<dim3(131),  dim3(128), 0, stream>>>(Wq, Wk, Wv, W1, b1, W2, b2, s1h);
    k_ownt <<<dim3(512),  dim3(256), 0, stream>>>(state0, W_own, b_own, s1h);
    k_grid <<<dim3(512),  dim3(256), 0, stream>>>(state1, W_grid, b_grid);
    k_main <<<dim3(2048), dim3(256), 0, stream>>>(state2, W_intr, b_intr, s1h, d_out);
}

// Round 8
// 282.881 us; speedup vs baseline: 2.9362x; 1.0768x over previous
//
#include <hip/hip_runtime.h>

typedef unsigned short ushort_t;
typedef __attribute__((ext_vector_type(8))) short bf16x8;   // 8 bf16 = 4 VGPRs
typedef __attribute__((ext_vector_type(4))) float f32x4;

__device__ __forceinline__ float bflo(unsigned u) { return __uint_as_float(u << 16); }
__device__ __forceinline__ float bfhi(unsigned u) { return __uint_as_float(u & 0xffff0000u); }
__device__ __forceinline__ float bfu(ushort_t s)  { return __uint_as_float((unsigned)s << 16); }
__device__ __forceinline__ ushort_t f2bf(float f) {
    unsigned u = __float_as_uint(f);
    u = u + 0x7fffu + ((u >> 16) & 1u);   // RNE
    return (ushort_t)(u >> 16);
}
__device__ __forceinline__ void unpack8(uint4 v, float* f) {
    f[0]=bflo(v.x); f[1]=bfhi(v.x); f[2]=bflo(v.y); f[3]=bfhi(v.y);
    f[4]=bflo(v.z); f[5]=bfhi(v.z); f[6]=bflo(v.w); f[7]=bfhi(v.w);
}

// dtype-agnostic loads: f32 != 0 -> buffer holds float32, else bf16.
__device__ __forceinline__ float load1(const void* p, size_t i, int f32) {
    return f32 ? ((const float*)p)[i] : bfu(((const ushort_t*)p)[i]);
}
__device__ __forceinline__ void load8(const void* p, size_t i, int f32, float* f) {
    if (f32) {
        const float4 a = *(const float4*)((const float*)p + i);
        const float4 b = *(const float4*)((const float*)p + i + 4);
        f[0]=a.x; f[1]=a.y; f[2]=a.z; f[3]=a.w;
        f[4]=b.x; f[5]=b.y; f[6]=b.z; f[7]=b.w;
    } else {
        unpack8(*(const uint4*)((const ushort_t*)p + i), f);
    }
}
__device__ __forceinline__ void load4(const void* p, size_t i, int f32, float* f) {
    if (f32) {
        const float4 a = *(const float4*)((const float*)p + i);
        f[0]=a.x; f[1]=a.y; f[2]=a.z; f[3]=a.w;
    } else {
        const uint2 u = *(const uint2*)((const ushort_t*)p + i);
        f[0]=bflo(u.x); f[1]=bfhi(u.x); f[2]=bflo(u.y); f[3]=bfhi(u.y);
    }
}

// Inline dtype probe (wave-uniform): decode first 128 u16 halves of state1 as
// bf16. Real-bf16 randn stays <6; fp32 mantissa halves explode >1e6 w.p. ~1.
__device__ __forceinline__ int detect_f32(const ushort_t* s1h) {
    const int ln = threadIdx.x & 63;
    float v = fmaxf(fabsf(bfu(s1h[ln])), fabsf(bfu(s1h[ln + 64])));
    bool big = !(v <= 1e6f);               // NaN/Inf/large -> true
    return __ballot(big) != 0ull;
}

#define B_TOT 8192

__device__ __attribute__((aligned(16))) float    g_M[128 * 128];
__device__ __attribute__((aligned(16))) float    g_Wc1[384 * 4];
__device__ __attribute__((aligned(16))) float    g_Wv2[128 * 4];
__device__ __attribute__((aligned(16))) float    g_bc[4];
__device__ __attribute__((aligned(16))) float    g_t[B_TOT * 128];
__device__ __attribute__((aligned(16))) float    g_ogc[B_TOT * 4];
__device__ __attribute__((aligned(16))) ushort_t g_oe[B_TOT * 128];

// ---------------------------------------------------------------------------
// K1: precompute M = Wq@Wk^T, Wc1 = W1@W2, Wv2 = Wv@Wc1[128:256], bc = b1@W2+b2
// ---------------------------------------------------------------------------
__global__ __launch_bounds__(128) void k_pre(
    const void* __restrict__ Wq, const void* __restrict__ Wk,
    const void* __restrict__ Wv, const void* __restrict__ W1,
    const void* __restrict__ b1, const void* __restrict__ W2,
    const void* __restrict__ b2, const ushort_t* __restrict__ s1h)
{
    __shared__ float wq_sh[128];
    __shared__ float w2_sh[512];
    __shared__ float wc1_mid[512];
    __shared__ float redc[128][4];
    const int tid = threadIdx.x;
    const int bx = blockIdx.x;
    const int f32 = detect_f32(s1h);

    if (bx < 128) {
        wq_sh[tid] = load1(Wq, bx*128 + tid, f32);
        __syncthreads();
        float acc = 0.f;
        #pragma unroll
        for (int c = 0; c < 16; ++c) {
            float f[8]; load8(Wk, (size_t)tid*128 + c*8, f32, f);
            #pragma unroll
            for (int j = 0; j < 8; ++j) acc = fmaf(wq_sh[c*8+j], f[j], acc);
        }
        g_M[bx*128 + tid] = acc;
    } else {
        const int rbase = (bx == 128) ? 0 : ((bx == 129) ? 128 : 256);
        for (int i = tid; i < 512; i += 128) w2_sh[i] = load1(W2, i, f32);
        __syncthreads();

        const int r = rbase + tid;
        float a[4] = {0.f, 0.f, 0.f, 0.f};
        #pragma unroll
        for (int c = 0; c < 16; ++c) {
            float f[8]; load8(W1, (size_t)r*128 + c*8, f32, f);
            #pragma unroll
            for (int j = 0; j < 8; ++j) {
                const int p = c*8 + j;
                #pragma unroll
                for (int q = 0; q < 4; ++q) a[q] = fmaf(f[j], w2_sh[p*4+q], a[q]);
            }
        }
        #pragma unroll
        for (int q = 0; q < 4; ++q) g_Wc1[r*4+q] = a[q];

        if (bx == 129) {
            #pragma unroll
            for (int q = 0; q < 4; ++q) wc1_mid[tid*4+q] = a[q];
            __syncthreads();
            float v[4] = {0.f, 0.f, 0.f, 0.f};
            #pragma unroll
            for (int c = 0; c < 16; ++c) {
                float f[8]; load8(Wv, (size_t)tid*128 + c*8, f32, f);
                #pragma unroll
                for (int j = 0; j < 8; ++j) {
                    const int i2 = c*8 + j;
                    #pragma unroll
                    for (int q = 0; q < 4; ++q) v[q] = fmaf(f[j], wc1_mid[i2*4+q], v[q]);
                }
            }
            #pragma unroll
            for (int q = 0; q < 4; ++q) g_Wv2[tid*4+q] = v[q];

            const float bv = load1(b1, tid, f32);
            #pragma unroll
            for (int q = 0; q < 4; ++q) redc[tid][q] = bv * w2_sh[tid*4+q];
            __syncthreads();
            for (int s = 64; s > 0; s >>= 1) {
                if (tid < s) {
                    #pragma unroll
                    for (int q = 0; q < 4; ++q) redc[tid][q] += redc[tid+s][q];
                }
                __syncthreads();
            }
            if (tid < 4) g_bc[tid] = redc[0][tid] + load1(b2, tid, f32);
        }
    }
}

// ---------------------------------------------------------------------------
// K2+K3 merged (k_og): blocks 0..511 do k_ownt's work, 512..1023 do k_grid's.
// Both depend only on k_pre; merging lets them co-schedule instead of
// serializing on the stream. LDS overlaid via raw buffer (max of the two).
// ---------------------------------------------------------------------------
struct OwntSmem {
    float s0sh[16*16];
    float wosh[16*128];
    float bosh[128];
    float oesh[16*129];
    float Mt[32][128];
};
struct GridSmem {
    float s1T[32][18];
    float wg[32][128];
    float part[32][16][4];
};

__global__ __launch_bounds__(256) void k_og(
    const void* __restrict__ state0, const void* __restrict__ W_own,
    const void* __restrict__ b_own, const void* __restrict__ state1,
    const void* __restrict__ W_grid, const void* __restrict__ b_grid,
    const ushort_t* __restrict__ s1h)
{
    __shared__ __attribute__((aligned(16))) char smem_raw[
        sizeof(OwntSmem) > sizeof(GridSmem) ? sizeof(OwntSmem) : sizeof(GridSmem)];
    const int tid = threadIdx.x;
    const int bxx = blockIdx.x;
    const int f32 = detect_f32(s1h);

    if (bxx < 512) {
        // ================= k_ownt body =================
        OwntSmem& S = *reinterpret_cast<OwntSmem*>(smem_raw);
        const int b0 = bxx * 16;

        if (tid < 32) {
            float f[8]; load8(state0, (size_t)b0*16 + tid*8, f32, f);
            #pragma unroll
            for (int j = 0; j < 8; ++j) S.s0sh[tid*8 + j] = f[j];
        }
        {
            float f[8]; load8(W_own, (size_t)tid*8, f32, f);
            #pragma unroll
            for (int j = 0; j < 8; ++j) S.wosh[tid*8 + j] = f[j];
        }
        if (tid < 128) S.bosh[tid] = load1(b_own, tid, f32);
        __syncthreads();

        #pragma unroll
        for (int kk = 0; kk < 8; ++kk) {
            const int idx = tid + kk*256;
            const int bi = idx >> 7, h = idx & 127;
            float acc = S.bosh[h];
            #pragma unroll
            for (int d = 0; d < 16; ++d) acc = fmaf(S.s0sh[bi*16+d], S.wosh[d*128+h], acc);
            acc = fmaxf(acc, 0.f);
            S.oesh[bi*129 + h] = acc;
            g_oe[(size_t)(b0+bi)*128 + h] = f2bf(acc);
        }

        const int bi0 = (tid >> 5) * 2;
        const int h0  = (tid & 31) * 4;
        float t00=0.f,t01=0.f,t02=0.f,t03=0.f,t10=0.f,t11=0.f,t12=0.f,t13=0.f;
        for (int kt = 0; kt < 128; kt += 32) {
            __syncthreads();
            #pragma unroll
            for (int c = 0; c < 4; ++c) {
                const int i = tid + c*256;
                const int kk = i >> 5;
                const int hh = (i & 31) * 4;
                *(float4*)&S.Mt[kk][hh] = *(const float4*)&g_M[(size_t)(kt+kk)*128 + hh];
            }
            __syncthreads();
            #pragma unroll
            for (int k = 0; k < 32; ++k) {
                const float4 mv = *(const float4*)&S.Mt[k][h0];
                const float a0 = S.oesh[(bi0+0)*129 + kt + k];
                const float a1 = S.oesh[(bi0+1)*129 + kt + k];
                t00=fmaf(a0,mv.x,t00); t01=fmaf(a0,mv.y,t01); t02=fmaf(a0,mv.z,t02); t03=fmaf(a0,mv.w,t03);
                t10=fmaf(a1,mv.x,t10); t11=fmaf(a1,mv.y,t11); t12=fmaf(a1,mv.z,t12); t13=fmaf(a1,mv.w,t13);
            }
        }
        *(float4*)&g_t[(size_t)(b0+bi0+0)*128 + h0] = make_float4(t00,t01,t02,t03);
        *(float4*)&g_t[(size_t)(b0+bi0+1)*128 + h0] = make_float4(t10,t11,t12,t13);
    } else {
        // ================= k_grid body =================
        GridSmem& S = *reinterpret_cast<GridSmem*>(smem_raw);
        const int b0 = (bxx - 512) * 16;

        const int bq = tid & 7;
        const int hq = tid >> 3;
        float a00=0.f,a01=0.f,a02=0.f,a03=0.f;
        float a10=0.f,a11=0.f,a12=0.f,a13=0.f;

        for (int kt = 0; kt < 512; kt += 32) {
            if (kt) __syncthreads();
            if (tid < 128) {
                const int bb = tid >> 3;
                const int kk = (tid & 7) * 4;
                float f[4];
                load4(state1, (size_t)(b0 + bb)*512 + kt + kk, f32, f);
                #pragma unroll
                for (int j = 0; j < 4; ++j) S.s1T[kk + j][bb] = f[j];
            }
            {
                #pragma unroll
                for (int c = 0; c < 4; ++c) {
                    const int i = tid + c*256;
                    const int kk = i >> 5;
                    const int hh = (i & 31) * 4;
                    float f[4];
                    load4(W_grid, (size_t)(kt + kk)*128 + hh, f32, f);
                    *(float4*)&S.wg[kk][hh] = make_float4(f[0], f[1], f[2], f[3]);
                }
            }
            __syncthreads();
            #pragma unroll 8
            for (int k = 0; k < 32; ++k) {
                const float x0 = S.s1T[k][bq*2 + 0];
                const float x1 = S.s1T[k][bq*2 + 1];
                const float4 w = *(const float4*)&S.wg[k][hq*4];
                a00=fmaf(x0,w.x,a00); a01=fmaf(x0,w.y,a01); a02=fmaf(x0,w.z,a02); a03=fmaf(x0,w.w,a03);
                a10=fmaf(x1,w.x,a10); a11=fmaf(x1,w.y,a11); a12=fmaf(x1,w.z,a12); a13=fmaf(x1,w.w,a13);
            }
        }

        float accs[2][4] = {{a00,a01,a02,a03},{a10,a11,a12,a13}};
        float pr[2][4] = {{0,0,0,0},{0,0,0,0}};
        #pragma unroll
        for (int jh = 0; jh < 4; ++jh) {
            const int h = hq*4 + jh;
            const float bg = load1(b_grid, h, f32);
            const float4 wc = *(const float4*)&g_Wc1[(256 + h)*4];
            #pragma unroll
            for (int ib = 0; ib < 2; ++ib) {
                const float og = fmaxf(accs[ib][jh] + bg, 0.f);
                pr[ib][0] = fmaf(og, wc.x, pr[ib][0]);
                pr[ib][1] = fmaf(og, wc.y, pr[ib][1]);
                pr[ib][2] = fmaf(og, wc.z, pr[ib][2]);
                pr[ib][3] = fmaf(og, wc.w, pr[ib][3]);
            }
        }
        __syncthreads();
        #pragma unroll
        for (int j = 0; j < 4; ++j) {
            S.part[hq][bq*2+0][j] = pr[0][j];
            S.part[hq][bq*2+1][j] = pr[1][j];
        }
        __syncthreads();
        if (tid < 64) {
            const int bb = tid >> 2, j = tid & 3;
            float s = 0.f;
            #pragma unroll
            for (int q = 0; q < 32; ++q) s += S.part[q][bb][j];
            g_ogc[(size_t)(b0 + bb)*4 + j] = s;
        }
    }
}

// ---------------------------------------------------------------------------
// K4 v2 (RESTORED VERBATIM from round 1 — best measured: 71.7us, VGPR 64,
// occ 36%). Rounds 3-7 established: every VALU-cutting restructure raised
// VGPR, cut occupancy, and lost net time (64/36%/71.7 -> 88/20%/85.5 ->
// 208/11%/129.5). The compiler's regalloc of THIS source (rematerializing A
// from global across the softmax) is the best allocation found. Do not edit.
// ---------------------------------------------------------------------------
__global__ __launch_bounds__(256) void k_main(
    const void* __restrict__ state2, const void* __restrict__ W_intr,
    const void* __restrict__ b_intr, const ushort_t* __restrict__ s1h,
    void* __restrict__ out_raw)
{
    __shared__ __attribute__((aligned(16))) ushort_t wib[128 * 40]; // [h][k] bf16
    const int tid = threadIdx.x;
    const int f32 = detect_f32(s1h);

    // stage W_intr^T (coalesced read [d][h], transposed write), pad k=20..31
    #pragma unroll
    for (int c = 0; c < 10; ++c) {
        const int idx = c*256 + tid;          // idx = d*128 + h
        const int d = idx >> 7, h = idx & 127;
        wib[h*40 + d] = f32 ? f2bf(((const float*)W_intr)[idx])
                            : ((const ushort_t*)W_intr)[idx];
    }
    if (tid < 128) {
        #pragma unroll
        for (int k = 20; k < 32; ++k) wib[tid*40 + k] = 0;
    }
    __syncthreads();

    const int wv = tid >> 6, ln = tid & 63, lq = ln >> 4, lc = ln & 15;
    const int b = blockIdx.x * 4 + wv;

    // per-lane constants: bias (h = th*16+lc) and t (pre-scaled by 1/sqrt(H))
    float bi_r[8], t_r[8];
    #pragma unroll
    for (int th = 0; th < 8; ++th) {
        bi_r[th] = load1(b_intr, th*16 + lc, f32);
        t_r[th]  = g_t[(size_t)b*128 + th*16 + lc] * 0.08838834764831845f;
    }

    // A fragments (row n = i*16+lc, cols k = lq*8..+7; k>=20 register zeros)
    bf16x8 A[8];
    unsigned msk[8];
    if (!f32) {
        const ushort_t* s2 = (const ushort_t*)state2;
        #pragma unroll
        for (int i = 0; i < 8; ++i) {
            const size_t rb = ((size_t)b*128 + i*16 + lc)*20 + lq*8;
            uint2 p0 = make_uint2(0u, 0u), p1 = make_uint2(0u, 0u);
            if (lq < 2)       { p0 = *(const uint2*)(s2 + rb); p1 = *(const uint2*)(s2 + rb + 4); }
            else if (lq == 2) { p0 = *(const uint2*)(s2 + rb); }
            union { bf16x8 v; uint2 u[2]; } cv;
            cv.u[0] = p0; cv.u[1] = p1;
            A[i] = cv.v;
            float s = bflo(p0.x)+bfhi(p0.x)+bflo(p0.y)+bfhi(p0.y)
                    + bflo(p1.x)+bfhi(p1.x)+bflo(p1.y)+bfhi(p1.y);
            s += __shfl_xor(s, 16);
            s += __shfl_xor(s, 32);
            msk[i] = (unsigned)(__ballot(s != 0.f) & 0xffffull);
        }
    } else {
        const float* s2 = (const float*)state2;
        #pragma unroll
        for (int i = 0; i < 8; ++i) {
            const size_t rb = ((size_t)b*128 + i*16 + lc)*20 + lq*8;
            float f[8] = {0.f,0.f,0.f,0.f,0.f,0.f,0.f,0.f};
            if (lq < 2) {
                const float4 a4 = *(const float4*)(s2 + rb);
                const float4 b4 = *(const float4*)(s2 + rb + 4);
                f[0]=a4.x; f[1]=a4.y; f[2]=a4.z; f[3]=a4.w;
                f[4]=b4.x; f[5]=b4.y; f[6]=b4.z; f[7]=b4.w;
            } else if (lq == 2) {
                const float4 a4 = *(const float4*)(s2 + rb);
                f[0]=a4.x; f[1]=a4.y; f[2]=a4.z; f[3]=a4.w;
            }
            union { bf16x8 v; ushort_t h[8]; } cv;
            float s = 0.f;
            #pragma unroll
            for (int j = 0; j < 8; ++j) { cv.h[j] = f2bf(f[j]); s += f[j]; }
            A[i] = cv.v;
            s += __shfl_xor(s, 16);
            s += __shfl_xor(s, 32);
            msk[i] = (unsigned)(__ballot(s != 0.f) & 0xffffull);
        }
    }

    const f32x4 zf = {0.f, 0.f, 0.f, 0.f};

    // ---- pass 1: score[n] = relu(s2@W_intr + b) . t --------------------
    float sc[8][4];
    #pragma unroll
    for (int i = 0; i < 8; ++i)
        #pragma unroll
        for (int r = 0; r < 4; ++r) sc[i][r] = 0.f;

    #pragma unroll
    for (int th = 0; th < 8; ++th) {
        const bf16x8 Bv = *(const bf16x8*)&wib[(th*16 + lc)*40 + lq*8];
        #pragma unroll
        for (int i = 0; i < 8; ++i) {
            const f32x4 acc = __builtin_amdgcn_mfma_f32_16x16x32_bf16(A[i], Bv, zf, 0, 0, 0);
            #pragma unroll
            for (int r = 0; r < 4; ++r)
                sc[i][r] = fmaf(fmaxf(acc[r] + bi_r[th], 0.f), t_r[th], sc[i][r]);
        }
    }
    // reduce over the 16 h-lanes (lc)
    #pragma unroll
    for (int off = 1; off < 16; off <<= 1)
        #pragma unroll
        for (int i = 0; i < 8; ++i)
            #pragma unroll
            for (int r = 0; r < 4; ++r)
                sc[i][r] += __shfl_xor(sc[i][r], off);

    // ---- softmax over n (masked), fully in registers -------------------
    float m = -1e30f;
    #pragma unroll
    for (int i = 0; i < 8; ++i)
        #pragma unroll
        for (int r = 0; r < 4; ++r)
            if ((msk[i] >> (lq*4 + r)) & 1) m = fmaxf(m, sc[i][r]);
    m = fmaxf(m, __shfl_xor(m, 16));
    m = fmaxf(m, __shfl_xor(m, 32));

    float den = 0.f;
    #pragma unroll
    for (int i = 0; i < 8; ++i)
        #pragma unroll
        for (int r = 0; r < 4; ++r) {
            float e = 0.f;
            if ((msk[i] >> (lq*4 + r)) & 1) e = __expf(fmaxf(sc[i][r] - m, -80.f));
            sc[i][r] = e;
            den += e;
        }
    den += __shfl_xor(den, 16);
    den += __shfl_xor(den, 32);
    const float rden = (den > 0.f) ? (1.f / den) : 0.f;
    #pragma unroll
    for (int i = 0; i < 8; ++i)
        #pragma unroll
        for (int r = 0; r < 4; ++r) sc[i][r] *= rden;   // sc = alpha

    // ---- pass 2: out4 += (alpha . x_e) * Wv2, recomputing x_e ----------
    float o4[4] = {0.f, 0.f, 0.f, 0.f};
    #pragma unroll
    for (int th = 0; th < 8; ++th) {
        const bf16x8 Bv = *(const bf16x8*)&wib[(th*16 + lc)*40 + lq*8];
        float up = 0.f;
        #pragma unroll
        for (int i = 0; i < 8; ++i) {
            const f32x4 acc = __builtin_amdgcn_mfma_f32_16x16x32_bf16(A[i], Bv, zf, 0, 0, 0);
            #pragma unroll
            for (int r = 0; r < 4; ++r)
                up = fmaf(sc[i][r], fmaxf(acc[r] + bi_r[th], 0.f), up);
        }
        const float4 w2 = *(const float4*)&g_Wv2[(th*16 + lc)*4];
        o4[0] = fmaf(up, w2.x, o4[0]);
        o4[1] = fmaf(up, w2.y, o4[1]);
        o4[2] = fmaf(up, w2.z, o4[2]);
        o4[3] = fmaf(up, w2.w, o4[3]);
    }

    // ---- own_e @ Wc1[0:128] term (h = ln and ln+64) --------------------
    {
        const float oe0 = bfu(g_oe[(size_t)b*128 + ln]);
        const float oe1 = bfu(g_oe[(size_t)b*128 + 64 + ln]);
        const float4 wA = *(const float4*)&g_Wc1[ln*4];
        const float4 wB = *(const float4*)&g_Wc1[(64 + ln)*4];
        o4[0] += oe0*wA.x + oe1*wB.x;
        o4[1] += oe0*wA.y + oe1*wB.y;
        o4[2] += oe0*wA.z + oe1*wB.z;
        o4[3] += oe0*wA.w + oe1*wB.w;
    }

    // ---- 64-lane reduce + write ---------------------------------------
    #pragma unroll
    for (int off = 1; off < 64; off <<= 1)
        #pragma unroll
        for (int q = 0; q < 4; ++q)
            o4[q] += __shfl_xor(o4[q], off);

    if (ln == 0) {
        const float4 og = *(const float4*)&g_ogc[(size_t)b*4];
        const float v0 = g_bc[0] + og.x + o4[0];
        const float v1 = g_bc[1] + og.y + o4[1];
        const float v2 = g_bc[2] + og.z + o4[2];
        const float v3 = g_bc[3] + og.w + o4[3];
        const float l0 = fminf(fmaxf(v0, -20.f), 2.f);
        const float l1 = fminf(fmaxf(v1, -20.f), 2.f);
        const float l2 = fminf(fmaxf(v2, -20.f), 2.f);
        const float l3 = fminf(fmaxf(v3, -20.f), 2.f);
        if (f32) {
            float* of = (float*)out_raw;
            *(float4*)&of[(size_t)b*4] = make_float4(v0, v1, v2, v3);
            *(float4*)&of[((size_t)B_TOT + b)*4] = make_float4(l0, l1, l2, l3);
        } else {
            ushort_t* os = (ushort_t*)out_raw;
            uint2 mw, lw;
            mw.x = (unsigned)f2bf(v0) | ((unsigned)f2bf(v1) << 16);
            mw.y = (unsigned)f2bf(v2) | ((unsigned)f2bf(v3) << 16);
            lw.x = (unsigned)f2bf(l0) | ((unsigned)f2bf(l1) << 16);
            lw.y = (unsigned)f2bf(l2) | ((unsigned)f2bf(l3) << 16);
            *(uint2*)&os[(size_t)b*4] = mw;
            *(uint2*)&os[((size_t)B_TOT + b)*4] = lw;
        }
    }
}

// ---------------------------------------------------------------------------
extern "C" void kernel_launch(void* const* d_in, const int* in_sizes, int n_in,
                              void* d_out, int out_size, void* d_ws, size_t ws_size,
                              hipStream_t stream)
{
    (void)in_sizes; (void)n_in; (void)out_size; (void)d_ws; (void)ws_size;
    const void* state0 = d_in[0];
    const void* state1 = d_in[1];
    const void* state2 = d_in[2];
    const void* W_own  = d_in[3];
    const void* b_own  = d_in[4];
    const void* W_intr = d_in[5];
    const void* b_intr = d_in[6];
    const void* W_grid = d_in[7];
    const void* b_grid = d_in[8];
    const void* Wq     = d_in[9];
    const void* Wk     = d_in[10];
    const void* Wv     = d_in[11];
    const void* W1     = d_in[12];
    const void* b1     = d_in[13];
    const void* W2     = d_in[14];
    const void* b2     = d_in[15];
    const ushort_t* s1h = (const ushort_t*)state1;

    k_pre  <<<dim3(131),  dim3(128), 0, stream>>>(Wq, Wk, Wv, W1, b1, W2, b2, s1h);
    k_og   <<<dim3(1024), dim3(256), 0, stream>>>(state0, W_own, b_own, state1, W_grid, b_grid, s1h);
    k_main <<<dim3(2048), dim3(256), 0, stream>>>(state2, W_intr, b_intr, s1h, d_out);
}